// Round 6
// baseline (210.587 us; speedup 1.0000x reference)
//
#include <hip/hip_runtime.h>

// BlockSparseFlashAttention — Phi-3-small blocksparse prefill, MI355X (gfx950)
// S=2048, H=32, HKV=8 (GQA x4), D=128, BLK=64, LOCAL=16, VERT=8, HEAD_SLIDE=1
//
// R12. Ledger: R6 63.4us (3 barriers, overlay). R11 71.0us (= R6 + reg
// transform, conflicts 1.26M->0 but VALU chain serialized -> overlay wins).
// Critical path measured ~2050cyc/tile, MFMA only ~340 -> overhead-bound.
// This round: kb-parity wave split.
//  - Both waves SAME qb (R7's different-qb coupling was the proven defect),
//    each owns all 64 q-rows (qt=4) and alternate active kb tiles.
//  - Each wave stages its own private 32KB K/V LDS region -> ZERO barriers
//    in the main loop; within-wave ordering via s_waitcnt + sched_barrier(0).
//  - stage(t+2) issued after tile-t LDS reads drain, BEFORE the 72
//    register-only PV MFMAs -> DMA latency hides under PV.
//  - tiles/wave halve (~9.3), MFMA/tile doubles (136) -> overhead amortized.
//  - End merge of partial (O,l) through LDS, one barrier pair.
//  - Datapaths all verified: R6 staging/swizzle/QK/PV/overlay formulas
//    (overlay now wave-private), R9 enumerator, exp2 no-max softmax,
//    l-via-ones-MFMA, XCD pin kvh=blk&7, heavy-qb-first.

typedef __bf16 bf16_t;
typedef __bf16 bf16x4 __attribute__((ext_vector_type(4)));
typedef __bf16 bf16x8 __attribute__((ext_vector_type(8)));
typedef float  fx4    __attribute__((ext_vector_type(4)));

#define SL2E_F 0.1275240614354876f   // (1/sqrt(128)) * log2(e)

__device__ inline void load_lds16(const bf16_t* g, bf16_t* l) {
    __builtin_amdgcn_global_load_lds(
        (const __attribute__((address_space(1))) void*)g,
        (__attribute__((address_space(3))) void*)l, 16, 0, 0);
}

// ---- fused pre-pass: K fp32->bf16 (same layout) + V -> V^T bf16 ----------
__global__ void prep_kernel(const float* __restrict__ K, const float* __restrict__ V,
                            bf16_t* __restrict__ Kb, bf16_t* __restrict__ VT)
{
    const int blk = blockIdx.x;
    // --- K convert: 16 elts/thread ---
    {
        const size_t base = (size_t)blk * 4096 + (size_t)threadIdx.x * 16;
        fx4 a0 = *(const fx4*)(K + base);
        fx4 a1 = *(const fx4*)(K + base + 4);
        fx4 a2 = *(const fx4*)(K + base + 8);
        fx4 a3 = *(const fx4*)(K + base + 12);
        bf16x8 f0, f1;
        f0[0]=(bf16_t)a0[0]; f0[1]=(bf16_t)a0[1]; f0[2]=(bf16_t)a0[2]; f0[3]=(bf16_t)a0[3];
        f0[4]=(bf16_t)a1[0]; f0[5]=(bf16_t)a1[1]; f0[6]=(bf16_t)a1[2]; f0[7]=(bf16_t)a1[3];
        f1[0]=(bf16_t)a2[0]; f1[1]=(bf16_t)a2[1]; f1[2]=(bf16_t)a2[2]; f1[3]=(bf16_t)a2[3];
        f1[4]=(bf16_t)a3[0]; f1[5]=(bf16_t)a3[1]; f1[6]=(bf16_t)a3[2]; f1[7]=(bf16_t)a3[3];
        *(bf16x8*)(Kb + base)     = f0;
        *(bf16x8*)(Kb + base + 8) = f1;
    }
    // --- V transpose 64x64 tile (s0: seq, c0: channel) ---
    __shared__ __align__(16) bf16_t T[64 * 72];
    const int s0 = (blk & 31) * 64;
    const int c0 = (blk >> 5) * 64;
    const int tx = threadIdx.x & 15, ty = threadIdx.x >> 4;
    fx4 a0 = *(const fx4*)(V + (size_t)(s0 + ty * 4 + 0) * 1024 + c0 + tx * 4);
    fx4 a1 = *(const fx4*)(V + (size_t)(s0 + ty * 4 + 1) * 1024 + c0 + tx * 4);
    fx4 a2 = *(const fx4*)(V + (size_t)(s0 + ty * 4 + 2) * 1024 + c0 + tx * 4);
    fx4 a3 = *(const fx4*)(V + (size_t)(s0 + ty * 4 + 3) * 1024 + c0 + tx * 4);
#pragma unroll
    for (int j = 0; j < 4; ++j) {
        bf16x4 f = { (bf16_t)a0[j], (bf16_t)a1[j], (bf16_t)a2[j], (bf16_t)a3[j] };
        *(bf16x4*)&T[(tx * 4 + j) * 72 + ty * 4] = f;
    }
    __syncthreads();
    const int c = threadIdx.x >> 2, part = threadIdx.x & 3;
    bf16x8 x0 = *(const bf16x8*)&T[c * 72 + part * 16];
    bf16x8 x1 = *(const bf16x8*)&T[c * 72 + part * 16 + 8];
    bf16_t* dst = VT + (size_t)(c0 + c) * 2048 + s0 + part * 16;
    *(bf16x8*)(dst)     = x0;
    *(bf16x8*)(dst + 8) = x1;
}

// ------------------------------- main kernel -------------------------------
__launch_bounds__(128, 1)
__global__ void bsfa_kernel(const float* __restrict__ Q,
                            const bf16_t* __restrict__ Kb,
                            const bf16_t* __restrict__ VT,
                            float* __restrict__ O)
{
    const int blk  = blockIdx.x;                // 1024 blocks
    const int kvh  = blk & 7;                   // XCD-pinned kv head
    const int h    = kvh * 4 + ((blk >> 3) & 3);
    const int qb   = 31 - (blk >> 5);           // heavy query blocks first
    const int tid  = threadIdx.x;               // 0..127
    const int w    = tid >> 6;                  // wave 0/1: kb-parity split
    const int lane = tid & 63;
    const int l15  = lane & 15;
    const int quad = lane >> 4;

    // per-wave private 32KB: [ K tile 16KB | V^T tile 16KB ]
    __shared__ __align__(16) bf16_t SMEM[2][16384];
    __shared__ float Lmerge[64];

    bf16_t* Ksw = &SMEM[w][0];
    bf16_t* Vsw = &SMEM[w][8192];
    bf16_t* Pt  = Ksw;                          // [64][72] overlay (K dead then)

    const int row0 = qb * 64;                   // wave covers all 64 rows

    const bf16_t* kg = Kb + (size_t)kvh * 128;              // K row stride 1024
    const bf16_t* vg = VT + ((size_t)kvh * 128) * 2048;     // V^T row stride 2048

    // ---- closed-form active-kb enumerator (R9-verified, wave-uniform) ----
    const int loc0 = (qb > 15) ? (qb - 15) : 0;
    const int kb0s = (8 - ((h + 1) & 7)) & 7;   // smallest kb with (kb+h+1)%8==0
    auto nxt = [&](int kb) -> int {
        if (kb < loc0) { const int t = kb + 8; return (t <= qb - 16) ? t : loc0; }
        return (kb < qb) ? (kb + 1) : -1;
    };

    int kb = (qb - 16 >= kb0s) ? kb0s : loc0;   // first active tile (always >=0)
    if (w == 1) kb = nxt(kb);                   // wave 1 takes odd positions

    // ---- per-wave staging into private LDS (R6-verified swizzle math) ----
    auto stage = [&](int t) {
        const bf16_t* kt_g = kg + ((size_t)t << 16);   // t*64*1024
        const bf16_t* vt_g = vg + ((size_t)t << 6);    // t*64
#pragma unroll
        for (int i = 0; i < 16; ++i) {
            const int chunk = i * 64 + lane;           // 16B chunk index 0..1023
            const int krow = chunk >> 4;
            const int kc   = (chunk & 15) ^ (krow & 15);   // XOR swizzle
            load_lds16(kt_g + (size_t)krow * 1024 + kc * 8, Ksw + (size_t)chunk * 8);
            const int vrow = chunk >> 3;
            const int vc   = (chunk & 7) ^ (vrow & 7);
            load_lds16(vt_g + (size_t)vrow * 2048 + vc * 8, Vsw + (size_t)chunk * 8);
        }
    };

    if (kb >= 0) stage(kb);      // first tile DMA flies under Q-frag loading

    // ---- Q fragments qt=4 (B operand of S^T = K*Q^T), scale*log2e folded ----
    bf16x8 qf[4][4];
#pragma unroll
    for (int qt = 0; qt < 4; ++qt) {
        const float* qp = Q + (size_t)(row0 + qt * 16 + l15) * 4096 + h * 128;
#pragma unroll
        for (int kc = 0; kc < 4; ++kc) {
            fx4 a = *(const fx4*)(qp + kc * 32 + quad * 8);
            fx4 b = *(const fx4*)(qp + kc * 32 + quad * 8 + 4);
            bf16x8 f;
            f[0] = (bf16_t)(a[0] * SL2E_F); f[1] = (bf16_t)(a[1] * SL2E_F);
            f[2] = (bf16_t)(a[2] * SL2E_F); f[3] = (bf16_t)(a[3] * SL2E_F);
            f[4] = (bf16_t)(b[0] * SL2E_F); f[5] = (bf16_t)(b[1] * SL2E_F);
            f[6] = (bf16_t)(b[2] * SL2E_F); f[7] = (bf16_t)(b[3] * SL2E_F);
            qf[qt][kc] = f;
        }
    }

    bf16x8 ones;
#pragma unroll
    for (int i = 0; i < 8; ++i) ones[i] = (bf16_t)1.0f;

    fx4 oacc[8][4];
    fx4 lacc[4];
    const fx4 zero4 = {0.0f, 0.0f, 0.0f, 0.0f};
#pragma unroll
    for (int dt = 0; dt < 8; ++dt)
#pragma unroll
        for (int qt = 0; qt < 4; ++qt) oacc[dt][qt] = zero4;
#pragma unroll
    for (int qt = 0; qt < 4; ++qt) lacc[qt] = zero4;

    while (kb >= 0) {
        int nkb = nxt(kb);                       // skip partner's tile
        if (nkb >= 0) nkb = nxt(nkb);

        // tile resident? (RAW: DMA -> ds_read; compiler can't see the dep)
        asm volatile("s_waitcnt vmcnt(0)" ::: "memory");
        __builtin_amdgcn_sched_barrier(0);

        // ---- S^T = K * Q^T (K frags from own swizzled LDS) ----
        fx4 sacc[4][4];
#pragma unroll
        for (int kt = 0; kt < 4; ++kt)
#pragma unroll
            for (int qt = 0; qt < 4; ++qt) sacc[kt][qt] = zero4;
#pragma unroll
        for (int kc = 0; kc < 4; ++kc)
#pragma unroll
            for (int kt = 0; kt < 4; ++kt) {
                bf16x8 kf = *(const bf16x8*)&Ksw[(kt * 16 + l15) * 128 + ((kc * 4 + quad) ^ l15) * 8];
#pragma unroll
                for (int qt = 0; qt < 4; ++qt)
                    sacc[kt][qt] = __builtin_amdgcn_mfma_f32_16x16x32_bf16(
                        kf, qf[qt][kc], sacc[kt][qt], 0, 0, 0);
            }

        // ---- causal mask on the diagonal block ----
        if (kb == qb) {
#pragma unroll
            for (int kt = 0; kt < 4; ++kt)
#pragma unroll
                for (int qt = 0; qt < 4; ++qt)
#pragma unroll
                    for (int r = 0; r < 4; ++r) {
                        const int k_in = kt * 16 + quad * 4 + r;
                        const int q_in = qt * 16 + l15;
                        if (q_in < k_in) sacc[kt][qt][r] = -1e30f;
                    }
        }

        // ---- no-max softmax: p = 2^s ----
#pragma unroll
        for (int kt = 0; kt < 4; ++kt)
#pragma unroll
            for (int qt = 0; qt < 4; ++qt)
#pragma unroll
                for (int r = 0; r < 4; ++r)
                    sacc[kt][qt][r] = exp2f(sacc[kt][qt][r]);

        // ---- P overlay on own K region (WAR: K ds_reads must drain) ----
        asm volatile("s_waitcnt lgkmcnt(0)" ::: "memory");
        __builtin_amdgcn_sched_barrier(0);
#pragma unroll
        for (int qt = 0; qt < 4; ++qt)
#pragma unroll
            for (int kt = 0; kt < 4; ++kt) {
                bf16x4 f = { (bf16_t)sacc[kt][qt][0], (bf16_t)sacc[kt][qt][1],
                             (bf16_t)sacc[kt][qt][2], (bf16_t)sacc[kt][qt][3] };
                *(bf16x4*)&Pt[(qt * 16 + l15) * 72 + kt * 16 + quad * 4] = f;
            }
        asm volatile("s_waitcnt lgkmcnt(0)" ::: "memory");
        __builtin_amdgcn_sched_barrier(0);

        // ---- re-read P as B-operand frags; V frags (all LDS reads batched) ----
        bf16x8 pf[4][2];
#pragma unroll
        for (int qt = 0; qt < 4; ++qt)
#pragma unroll
            for (int kcg = 0; kcg < 2; ++kcg)
                pf[qt][kcg] = *(const bf16x8*)&Pt[(qt * 16 + l15) * 72 + kcg * 32 + quad * 8];
        bf16x8 vf[2][8];
#pragma unroll
        for (int kcg = 0; kcg < 2; ++kcg)
#pragma unroll
            for (int dt = 0; dt < 8; ++dt)
                vf[kcg][dt] = *(const bf16x8*)&Vsw[(dt * 16 + l15) * 64 + ((kcg * 4 + quad) ^ (l15 & 7)) * 8];

        // all LDS reads of this tile drained -> safe to overwrite via DMA
        asm volatile("s_waitcnt lgkmcnt(0)" ::: "memory");
        __builtin_amdgcn_sched_barrier(0);
        if (nkb >= 0) stage(nkb);        // DMA flies under the PV MFMAs below

        // ---- O^T += V^T * P^T ; l += ones * P^T (register-only) ----
#pragma unroll
        for (int kcg = 0; kcg < 2; ++kcg) {
#pragma unroll
            for (int dt = 0; dt < 8; ++dt)
#pragma unroll
                for (int qt = 0; qt < 4; ++qt)
                    oacc[dt][qt] = __builtin_amdgcn_mfma_f32_16x16x32_bf16(
                        vf[kcg][dt], pf[qt][kcg], oacc[dt][qt], 0, 0, 0);
#pragma unroll
            for (int qt = 0; qt < 4; ++qt)
                lacc[qt] = __builtin_amdgcn_mfma_f32_16x16x32_bf16(
                    ones, pf[qt][kcg], lacc[qt], 0, 0, 0);
        }

        kb = nkb;
    }

    // ---- merge the two waves' partial (O, l) via LDS; wave 0 stores ----
    __syncthreads();
    if (w == 1) {
        float* Obuf = (float*)&SMEM[1][0];       // wave 1's region, now dead
#pragma unroll
        for (int dt = 0; dt < 8; ++dt)
#pragma unroll
            for (int qt = 0; qt < 4; ++qt)
                *(fx4*)&Obuf[(((dt * 4 + qt) * 64) + lane) * 4] = oacc[dt][qt];
        if (quad == 0) {
#pragma unroll
            for (int qt = 0; qt < 4; ++qt) Lmerge[qt * 16 + l15] = lacc[qt][0];
        }
    }
    __syncthreads();
    if (w == 0) {
        const float* Obuf = (const float*)&SMEM[1][0];
#pragma unroll
        for (int qt = 0; qt < 4; ++qt) {
            const float inv = 1.0f / (lacc[qt][0] + Lmerge[qt * 16 + l15]);
#pragma unroll
            for (int dt = 0; dt < 8; ++dt) {
                fx4 o = (oacc[dt][qt] + *(const fx4*)&Obuf[(((dt * 4 + qt) * 64) + lane) * 4]) * inv;
                *(fx4*)(O + (size_t)(row0 + qt * 16 + l15) * 4096 + h * 128 + dt * 16 + quad * 4) = o;
            }
        }
    }
}

extern "C" void kernel_launch(void* const* d_in, const int* in_sizes, int n_in,
                              void* d_out, int out_size, void* d_ws, size_t ws_size,
                              hipStream_t stream) {
    (void)in_sizes; (void)n_in; (void)ws_size; (void)out_size;
    const float* q = (const float*)d_in[0];
    const float* k = (const float*)d_in[1];
    const float* v = (const float*)d_in[2];
    float* o = (float*)d_out;

    bf16_t* Kb = (bf16_t*)d_ws;                       // [2048][1024] bf16 = 4 MB
    bf16_t* VT = Kb + (size_t)2048 * 1024;            // [1024][2048] bf16 = 4 MB

    prep_kernel<<<dim3(512), dim3(256), 0, stream>>>(k, v, Kb, VT);
    bsfa_kernel<<<dim3(1024), dim3(128), 0, stream>>>(q, Kb, VT, o);
}

// Round 7
// 159.771 us; speedup vs baseline: 1.3181x; 1.3181x over previous
//
#include <hip/hip_runtime.h>

// BlockSparseFlashAttention — Phi-3-small blocksparse prefill, MI355X (gfx950)
// S=2048, H=32, HKV=8 (GQA x4), D=128, BLK=64, LOCAL=16, VERT=8, HEAD_SLIDE=1
//
// R13. Ledger: R6 63.4us best. Attributed failures: R7 different-qb coupling;
// R9 64KB LDS -> 2 blocks/CU; R10 VGPR-cap V-load sinking; R11 serial permlane
// chain; R12 qt=4 register spill (VGPR=256, scratch traffic in FETCH/WRITE).
// Single delta vs R6: the tile DMA is moved from "issue -> immediately drain
// at barrier" (full ~500-600cyc exposed per tile) to "issue at the point all
// of tile t's LDS reads are in registers" — zero extra LDS, same 3 barriers:
//   QK -> barA (K reads done) -> P overlay -> pf+vf batched to regs ->
//   barB (all LDS reads done) -> stage(t+1) -> PV reg-only (hides DMA) ->
//   barC (drains remainder).
// vf batching = +64 VGPR at qt=2 (~190 total, under the (128,2) cap of 256;
// R12's spill was qt=4's extra 128). R9/R10-verified closed-form kb
// enumerator replaces the scan (prefetch needs lookahead).
// Falsifier: VGPR>=240 or WRITE_SIZE >> 33MB => spill => revert vf batching.

typedef __bf16 bf16_t;
typedef __bf16 bf16x4 __attribute__((ext_vector_type(4)));
typedef __bf16 bf16x8 __attribute__((ext_vector_type(8)));
typedef float  fx4    __attribute__((ext_vector_type(4)));

#define SL2E_F 0.1275240614354876f   // (1/sqrt(128)) * log2(e)

__device__ inline void load_lds16(const bf16_t* g, bf16_t* l) {
    __builtin_amdgcn_global_load_lds(
        (const __attribute__((address_space(1))) void*)g,
        (__attribute__((address_space(3))) void*)l, 16, 0, 0);
}

// ---- fused pre-pass: K fp32->bf16 (same layout) + V -> V^T bf16 ----------
// grid 512 x 256thr. Each WG: 4096 K elts converted + one 64x64 V tile
// transposed into VT [1024][2048].
__global__ void prep_kernel(const float* __restrict__ K, const float* __restrict__ V,
                            bf16_t* __restrict__ Kb, bf16_t* __restrict__ VT)
{
    const int blk = blockIdx.x;
    // --- K convert: 16 elts/thread ---
    {
        const size_t base = (size_t)blk * 4096 + (size_t)threadIdx.x * 16;
        fx4 a0 = *(const fx4*)(K + base);
        fx4 a1 = *(const fx4*)(K + base + 4);
        fx4 a2 = *(const fx4*)(K + base + 8);
        fx4 a3 = *(const fx4*)(K + base + 12);
        bf16x8 f0, f1;
        f0[0]=(bf16_t)a0[0]; f0[1]=(bf16_t)a0[1]; f0[2]=(bf16_t)a0[2]; f0[3]=(bf16_t)a0[3];
        f0[4]=(bf16_t)a1[0]; f0[5]=(bf16_t)a1[1]; f0[6]=(bf16_t)a1[2]; f0[7]=(bf16_t)a1[3];
        f1[0]=(bf16_t)a2[0]; f1[1]=(bf16_t)a2[1]; f1[2]=(bf16_t)a2[2]; f1[3]=(bf16_t)a2[3];
        f1[4]=(bf16_t)a3[0]; f1[5]=(bf16_t)a3[1]; f1[6]=(bf16_t)a3[2]; f1[7]=(bf16_t)a3[3];
        *(bf16x8*)(Kb + base)     = f0;
        *(bf16x8*)(Kb + base + 8) = f1;
    }
    // --- V transpose 64x64 tile (s0: seq, c0: channel) ---
    __shared__ __align__(16) bf16_t T[64 * 72];
    const int s0 = (blk & 31) * 64;
    const int c0 = (blk >> 5) * 64;
    const int tx = threadIdx.x & 15, ty = threadIdx.x >> 4;
    fx4 a0 = *(const fx4*)(V + (size_t)(s0 + ty * 4 + 0) * 1024 + c0 + tx * 4);
    fx4 a1 = *(const fx4*)(V + (size_t)(s0 + ty * 4 + 1) * 1024 + c0 + tx * 4);
    fx4 a2 = *(const fx4*)(V + (size_t)(s0 + ty * 4 + 2) * 1024 + c0 + tx * 4);
    fx4 a3 = *(const fx4*)(V + (size_t)(s0 + ty * 4 + 3) * 1024 + c0 + tx * 4);
#pragma unroll
    for (int j = 0; j < 4; ++j) {
        bf16x4 f = { (bf16_t)a0[j], (bf16_t)a1[j], (bf16_t)a2[j], (bf16_t)a3[j] };
        *(bf16x4*)&T[(tx * 4 + j) * 72 + ty * 4] = f;
    }
    __syncthreads();
    const int c = threadIdx.x >> 2, part = threadIdx.x & 3;
    bf16x8 x0 = *(const bf16x8*)&T[c * 72 + part * 16];
    bf16x8 x1 = *(const bf16x8*)&T[c * 72 + part * 16 + 8];
    bf16_t* dst = VT + (size_t)(c0 + c) * 2048 + s0 + part * 16;
    *(bf16x8*)(dst)     = x0;
    *(bf16x8*)(dst + 8) = x1;
}

// ------------------------------- main kernel -------------------------------
__launch_bounds__(128, 2)
__global__ void bsfa_kernel(const float* __restrict__ Q,
                            const bf16_t* __restrict__ Kb,
                            const bf16_t* __restrict__ VT,
                            float* __restrict__ O)
{
    const int blk  = blockIdx.x;
    const int kvh  = blk & 7;                   // XCD-pinned kv head
    const int h    = kvh * 4 + ((blk >> 3) & 3);
    const int qb   = 31 - (blk >> 5);           // heavy query blocks first
    const int tid  = threadIdx.x;               // 0..127
    const int rh   = tid >> 6;                  // wave = row half (32 rows)
    const int lane = tid & 63;
    const int l15  = lane & 15;
    const int quad = lane >> 4;

    __shared__ __align__(16) bf16_t Ks[64 * 128];   // K tile (16 KB); P overlay
    __shared__ __align__(16) bf16_t Vs[128 * 64];   // V^T tile (16 KB)

    bf16_t* Pt = &Ks[rh * 2304];      // wave-private P [32][72] (4608 elts tot)

    const int row0 = qb * 64 + rh * 32;

    const bf16_t* kg = Kb + (size_t)kvh * 128;              // K row stride 1024
    const bf16_t* vg = VT + ((size_t)kvh * 128) * 2048;     // V^T row stride 2048

    // ---- Q fragments (B operand of S^T = K*Q^T), scale*log2e folded in ----
    bf16x8 qf[2][4];
#pragma unroll
    for (int qt = 0; qt < 2; ++qt) {
        const float* qp = Q + (size_t)(row0 + qt * 16 + l15) * 4096 + h * 128;
#pragma unroll
        for (int kc = 0; kc < 4; ++kc) {
            fx4 a = *(const fx4*)(qp + kc * 32 + quad * 8);
            fx4 b = *(const fx4*)(qp + kc * 32 + quad * 8 + 4);
            bf16x8 f;
            f[0] = (bf16_t)(a[0] * SL2E_F); f[1] = (bf16_t)(a[1] * SL2E_F);
            f[2] = (bf16_t)(a[2] * SL2E_F); f[3] = (bf16_t)(a[3] * SL2E_F);
            f[4] = (bf16_t)(b[0] * SL2E_F); f[5] = (bf16_t)(b[1] * SL2E_F);
            f[6] = (bf16_t)(b[2] * SL2E_F); f[7] = (bf16_t)(b[3] * SL2E_F);
            qf[qt][kc] = f;
        }
    }

    // ones fragment: A-operand for the l-via-MFMA trick
    bf16x8 ones;
#pragma unroll
    for (int i = 0; i < 8; ++i) ones[i] = (bf16_t)1.0f;

    fx4 oacc[8][2];
    fx4 lacc[2];
    const fx4 zero4 = {0.0f, 0.0f, 0.0f, 0.0f};
#pragma unroll
    for (int dt = 0; dt < 8; ++dt)
#pragma unroll
        for (int qt = 0; qt < 2; ++qt)
            oacc[dt][qt] = zero4;
    lacc[0] = zero4; lacc[1] = zero4;

    // ---- staging (R6-verified swizzle math; single buffer) ----
    auto stage = [&](int t) {
        const bf16_t* kt_g = kg + ((size_t)t << 16);   // t*64*1024
        const bf16_t* vt_g = vg + ((size_t)t << 6);    // t*64
#pragma unroll
        for (int i = 0; i < 8; ++i) {
            const int chunk = i * 128 + tid;            // 16B chunk index
            const int krow = chunk >> 4;
            const int kc   = (chunk & 15) ^ (krow & 15);   // XOR swizzle
            load_lds16(kt_g + (size_t)krow * 1024 + kc * 8, Ks + (size_t)chunk * 8);
            const int vrow = chunk >> 3;
            const int vc   = (chunk & 7) ^ (vrow & 7);
            load_lds16(vt_g + (size_t)vrow * 2048 + vc * 8, Vs + (size_t)chunk * 8);
        }
    };

    // ---- closed-form active-kb enumerator (R9/R10-verified, block-uniform) ----
    const int loc0 = (qb > 15) ? (qb - 15) : 0;
    const int kb0s = (8 - ((h + 1) & 7)) & 7;     // smallest kb with (kb+h+1)%8==0
    auto nxt = [&](int kb) -> int {
        if (kb < loc0) { const int t = kb + 8; return (t <= qb - 16) ? t : loc0; }
        return (kb < qb) ? (kb + 1) : -1;
    };

    int kb = (qb - 16 >= kb0s) ? kb0s : loc0;    // first active tile (>=0 always)
    stage(kb);
    __syncthreads();                 // prologue: cold drain (once)

    while (kb >= 0) {
        const int nkb = nxt(kb);

        // ---- S^T = K * Q^T (K frags from swizzled LDS) ----
        fx4 sacc[4][2];
#pragma unroll
        for (int kt = 0; kt < 4; ++kt)
#pragma unroll
            for (int qt = 0; qt < 2; ++qt)
                sacc[kt][qt] = zero4;
#pragma unroll
        for (int kc = 0; kc < 4; ++kc)
#pragma unroll
            for (int kt = 0; kt < 4; ++kt) {
                bf16x8 kf = *(const bf16x8*)&Ks[(kt * 16 + l15) * 128 + (((kc * 4 + quad) ^ l15)) * 8];
#pragma unroll
                for (int qt = 0; qt < 2; ++qt)
                    sacc[kt][qt] = __builtin_amdgcn_mfma_f32_16x16x32_bf16(
                        kf, qf[qt][kc], sacc[kt][qt], 0, 0, 0);
            }

        // ---- causal mask on the diagonal block (log2-domain scores) ----
        if (kb == qb) {
#pragma unroll
            for (int kt = 0; kt < 4; ++kt)
#pragma unroll
                for (int qt = 0; qt < 2; ++qt)
#pragma unroll
                    for (int r = 0; r < 4; ++r) {
                        const int k_in = kt * 16 + quad * 4 + r;
                        const int q_in = rh * 32 + qt * 16 + l15;
                        if (q_in < k_in) sacc[kt][qt][r] = -1e30f;
                    }
        }

        // ---- no-max softmax: p = 2^s (no row reduce — l comes from MFMA) ----
#pragma unroll
        for (int kt = 0; kt < 4; ++kt)
#pragma unroll
            for (int qt = 0; qt < 2; ++qt)
#pragma unroll
                for (int r = 0; r < 4; ++r)
                    sacc[kt][qt][r] = exp2f(sacc[kt][qt][r]);

        __syncthreads();   // bar A: all K reads (both waves) done before P overlay

        // ---- P -> wave-private LDS overlay ----
#pragma unroll
        for (int qt = 0; qt < 2; ++qt)
#pragma unroll
            for (int kt = 0; kt < 4; ++kt) {
                bf16x4 f = { (bf16_t)sacc[kt][qt][0], (bf16_t)sacc[kt][qt][1],
                             (bf16_t)sacc[kt][qt][2], (bf16_t)sacc[kt][qt][3] };
                *(bf16x4*)&Pt[(qt * 16 + l15) * 72 + kt * 16 + quad * 4] = f;
            }
        __asm__ __volatile__("s_waitcnt lgkmcnt(0)" ::: "memory");
        __builtin_amdgcn_sched_barrier(0);

        // ---- batch ALL remaining tile-t LDS reads into registers ----
        bf16x8 pf[2][2];
#pragma unroll
        for (int qt = 0; qt < 2; ++qt)
#pragma unroll
            for (int kcg = 0; kcg < 2; ++kcg)
                pf[qt][kcg] = *(const bf16x8*)&Pt[(qt * 16 + l15) * 72 + kcg * 32 + quad * 8];
        bf16x8 vf[2][8];
#pragma unroll
        for (int kcg = 0; kcg < 2; ++kcg)
#pragma unroll
            for (int dt = 0; dt < 8; ++dt)
                vf[kcg][dt] = *(const bf16x8*)&Vs[(dt * 16 + l15) * 64 + (((kcg * 4 + quad) ^ (l15 & 7))) * 8];

        __syncthreads();   // bar B: every LDS read of tile t is complete
                           // (syncthreads drains lgkm) -> buffers are dead

        if (nkb >= 0) stage(nkb);   // issue DMA NOW; PV below hides its latency

        // ---- O^T += V^T * P^T ; l += ones * P^T (register-only MFMAs) ----
#pragma unroll
        for (int kcg = 0; kcg < 2; ++kcg) {
#pragma unroll
            for (int dt = 0; dt < 8; ++dt)
#pragma unroll
                for (int qt = 0; qt < 2; ++qt)
                    oacc[dt][qt] = __builtin_amdgcn_mfma_f32_16x16x32_bf16(
                        vf[kcg][dt], pf[qt][kcg], oacc[dt][qt], 0, 0, 0);
#pragma unroll
            for (int qt = 0; qt < 2; ++qt)
                lacc[qt] = __builtin_amdgcn_mfma_f32_16x16x32_bf16(
                    ones, pf[qt][kcg], lacc[qt], 0, 0, 0);
        }

        __syncthreads();   // bar C: drains the (mostly landed) next-tile DMA
        kb = nkb;
    }

    // ---- epilogue: each wave stores its own 32 rows ----
    const float inv0 = 1.0f / lacc[0][0];   // all rows of lacc are identical
    const float inv1 = 1.0f / lacc[1][0];
#pragma unroll
    for (int dt = 0; dt < 8; ++dt)
#pragma unroll
        for (int qt = 0; qt < 2; ++qt) {
            const float inv = qt ? inv1 : inv0;
            fx4 o = oacc[dt][qt] * inv;
            *(fx4*)(O + (size_t)(row0 + qt * 16 + l15) * 4096 + h * 128 + dt * 16 + quad * 4) = o;
        }
}

extern "C" void kernel_launch(void* const* d_in, const int* in_sizes, int n_in,
                              void* d_out, int out_size, void* d_ws, size_t ws_size,
                              hipStream_t stream) {
    (void)in_sizes; (void)n_in; (void)ws_size; (void)out_size;
    const float* q = (const float*)d_in[0];
    const float* k = (const float*)d_in[1];
    const float* v = (const float*)d_in[2];
    float* o = (float*)d_out;

    bf16_t* Kb = (bf16_t*)d_ws;                       // [2048][1024] bf16 = 4 MB
    bf16_t* VT = Kb + (size_t)2048 * 1024;            // [1024][2048] bf16 = 4 MB

    prep_kernel<<<dim3(512), dim3(256), 0, stream>>>(k, v, Kb, VT);
    bsfa_kernel<<<dim3(1024), dim3(128), 0, stream>>>(q, Kb, VT, o);
}

// Round 8
// 144.095 us; speedup vs baseline: 1.4614x; 1.1088x over previous
//
#include <hip/hip_runtime.h>

// BlockSparseFlashAttention — Phi-3-small blocksparse prefill, MI355X (gfx950)
// S=2048, H=32, HKV=8 (GQA x4), D=128, BLK=64, LOCAL=16, VERT=8, HEAD_SLIDE=1
//
// R14. Ledger: R6 63.4us best. Attributed failures: R7 different-qb coupling;
// R9 64KB LDS -> 2 blocks/CU; R10 VGPR-cap V-load sinking; R11 serial permlane
// chain; R12 qt=4 spill; R13 vf-batching spill (compiler pinned VGPR=128,
// +16MB scratch traffic). Conclusion: register-batching V is dead; R6's
// overlay + in-PV-loop V reads is the proven inner structure.
// Single delta vs R6 (zero registers, zero LDS): counted-vmcnt K/V drain
// split. R6 issued 16 DMA chunks then drained ALL at barrier 1, but QK only
// needs K. Now: issue 8 K loads, then 8 V loads; s_waitcnt vmcnt(8) waits
// only the oldest 8 (=K); raw s_barrier; QK runs while V flies; barrier 2
// (__syncthreads, vmcnt 0) drains V for free after ~550cyc of QK+mask+exp.
// sched_barrier(0) pins K-loop/V-loop emission order and blocks ds_read
// hoisting above the raw barrier (rule 18).
// Health check: WRITE_SIZE must return to 32768 KB, VGPR ~112.

typedef __bf16 bf16_t;
typedef __bf16 bf16x4 __attribute__((ext_vector_type(4)));
typedef __bf16 bf16x8 __attribute__((ext_vector_type(8)));
typedef float  fx4    __attribute__((ext_vector_type(4)));

#define SL2E_F 0.1275240614354876f   // (1/sqrt(128)) * log2(e)

__device__ inline void load_lds16(const bf16_t* g, bf16_t* l) {
    __builtin_amdgcn_global_load_lds(
        (const __attribute__((address_space(1))) void*)g,
        (__attribute__((address_space(3))) void*)l, 16, 0, 0);
}

// ---- fused pre-pass: K fp32->bf16 (same layout) + V -> V^T bf16 ----------
// grid 512 x 256thr. Each WG: 4096 K elts converted + one 64x64 V tile
// transposed into VT [1024][2048].
__global__ void prep_kernel(const float* __restrict__ K, const float* __restrict__ V,
                            bf16_t* __restrict__ Kb, bf16_t* __restrict__ VT)
{
    const int blk = blockIdx.x;
    // --- K convert: 16 elts/thread ---
    {
        const size_t base = (size_t)blk * 4096 + (size_t)threadIdx.x * 16;
        fx4 a0 = *(const fx4*)(K + base);
        fx4 a1 = *(const fx4*)(K + base + 4);
        fx4 a2 = *(const fx4*)(K + base + 8);
        fx4 a3 = *(const fx4*)(K + base + 12);
        bf16x8 f0, f1;
        f0[0]=(bf16_t)a0[0]; f0[1]=(bf16_t)a0[1]; f0[2]=(bf16_t)a0[2]; f0[3]=(bf16_t)a0[3];
        f0[4]=(bf16_t)a1[0]; f0[5]=(bf16_t)a1[1]; f0[6]=(bf16_t)a1[2]; f0[7]=(bf16_t)a1[3];
        f1[0]=(bf16_t)a2[0]; f1[1]=(bf16_t)a2[1]; f1[2]=(bf16_t)a2[2]; f1[3]=(bf16_t)a2[3];
        f1[4]=(bf16_t)a3[0]; f1[5]=(bf16_t)a3[1]; f1[6]=(bf16_t)a3[2]; f1[7]=(bf16_t)a3[3];
        *(bf16x8*)(Kb + base)     = f0;
        *(bf16x8*)(Kb + base + 8) = f1;
    }
    // --- V transpose 64x64 tile (s0: seq, c0: channel) ---
    __shared__ __align__(16) bf16_t T[64 * 72];
    const int s0 = (blk & 31) * 64;
    const int c0 = (blk >> 5) * 64;
    const int tx = threadIdx.x & 15, ty = threadIdx.x >> 4;
    fx4 a0 = *(const fx4*)(V + (size_t)(s0 + ty * 4 + 0) * 1024 + c0 + tx * 4);
    fx4 a1 = *(const fx4*)(V + (size_t)(s0 + ty * 4 + 1) * 1024 + c0 + tx * 4);
    fx4 a2 = *(const fx4*)(V + (size_t)(s0 + ty * 4 + 2) * 1024 + c0 + tx * 4);
    fx4 a3 = *(const fx4*)(V + (size_t)(s0 + ty * 4 + 3) * 1024 + c0 + tx * 4);
#pragma unroll
    for (int j = 0; j < 4; ++j) {
        bf16x4 f = { (bf16_t)a0[j], (bf16_t)a1[j], (bf16_t)a2[j], (bf16_t)a3[j] };
        *(bf16x4*)&T[(tx * 4 + j) * 72 + ty * 4] = f;
    }
    __syncthreads();
    const int c = threadIdx.x >> 2, part = threadIdx.x & 3;
    bf16x8 x0 = *(const bf16x8*)&T[c * 72 + part * 16];
    bf16x8 x1 = *(const bf16x8*)&T[c * 72 + part * 16 + 8];
    bf16_t* dst = VT + (size_t)(c0 + c) * 2048 + s0 + part * 16;
    *(bf16x8*)(dst)     = x0;
    *(bf16x8*)(dst + 8) = x1;
}

// ------------------------------- main kernel -------------------------------
__launch_bounds__(128, 2)
__global__ void bsfa_kernel(const float* __restrict__ Q,
                            const bf16_t* __restrict__ Kb,
                            const bf16_t* __restrict__ VT,
                            float* __restrict__ O)
{
    const int blk  = blockIdx.x;
    const int kvh  = blk & 7;                   // XCD-pinned kv head
    const int h    = kvh * 4 + ((blk >> 3) & 3);
    const int qb   = 31 - (blk >> 5);           // heavy query blocks first
    const int tid  = threadIdx.x;               // 0..127
    const int rh   = tid >> 6;                  // wave = row half (32 rows)
    const int lane = tid & 63;
    const int l15  = lane & 15;
    const int quad = lane >> 4;

    __shared__ __align__(16) bf16_t Ks[64 * 128];   // swizzled K tile; P overlay
    __shared__ __align__(16) bf16_t Vs[128 * 64];   // swizzled V^T tile

    bf16_t* Pt = &Ks[rh * 2304];      // wave-private P [32][72] (4608 elts tot)

    const int row0 = qb * 64 + rh * 32;

    const bf16_t* kg = Kb + (size_t)kvh * 128;              // K row stride 1024
    const bf16_t* vg = VT + ((size_t)kvh * 128) * 2048;     // V^T row stride 2048

    // ---- Q fragments (B operand of S^T = K*Q^T), scale*log2e folded in ----
    bf16x8 qf[2][4];
#pragma unroll
    for (int qt = 0; qt < 2; ++qt) {
        const float* qp = Q + (size_t)(row0 + qt * 16 + l15) * 4096 + h * 128;
#pragma unroll
        for (int kc = 0; kc < 4; ++kc) {
            fx4 a = *(const fx4*)(qp + kc * 32 + quad * 8);
            fx4 b = *(const fx4*)(qp + kc * 32 + quad * 8 + 4);
            bf16x8 f;
            f[0] = (bf16_t)(a[0] * SL2E_F); f[1] = (bf16_t)(a[1] * SL2E_F);
            f[2] = (bf16_t)(a[2] * SL2E_F); f[3] = (bf16_t)(a[3] * SL2E_F);
            f[4] = (bf16_t)(b[0] * SL2E_F); f[5] = (bf16_t)(b[1] * SL2E_F);
            f[6] = (bf16_t)(b[2] * SL2E_F); f[7] = (bf16_t)(b[3] * SL2E_F);
            qf[qt][kc] = f;
        }
    }

    // ones fragment: A-operand for the l-via-MFMA trick
    bf16x8 ones;
#pragma unroll
    for (int i = 0; i < 8; ++i) ones[i] = (bf16_t)1.0f;

    fx4 oacc[8][2];
    fx4 lacc[2];
    const fx4 zero4 = {0.0f, 0.0f, 0.0f, 0.0f};
#pragma unroll
    for (int dt = 0; dt < 8; ++dt)
#pragma unroll
        for (int qt = 0; qt < 2; ++qt)
            oacc[dt][qt] = zero4;
    lacc[0] = zero4; lacc[1] = zero4;

    for (int kb = 0; kb <= qb; ++kb) {
        if (!((qb - kb < 16) || (((kb + h + 1) & 7) == 0))) continue;

        // ---- DMA-stage: 8 K chunks FIRST, then 8 V chunks (order pinned) ----
        {
            const bf16_t* kt_g = kg + ((size_t)kb << 16);   // kb*64*1024
            const bf16_t* vt_g = vg + ((size_t)kb << 6);    // kb*64
#pragma unroll
            for (int i = 0; i < 8; ++i) {
                const int chunk = i * 128 + tid;            // 16B chunk index
                const int krow = chunk >> 4;
                const int kc   = (chunk & 15) ^ (krow & 15);   // XOR swizzle
                load_lds16(kt_g + (size_t)krow * 1024 + kc * 8, Ks + (size_t)chunk * 8);
            }
            __builtin_amdgcn_sched_barrier(0);   // keep K issues before V issues
#pragma unroll
            for (int i = 0; i < 8; ++i) {
                const int chunk = i * 128 + tid;
                const int vrow = chunk >> 3;
                const int vc   = (chunk & 7) ^ (vrow & 7);
                load_lds16(vt_g + (size_t)vrow * 2048 + vc * 8, Vs + (size_t)chunk * 8);
            }
        }
        // barrier 1 (counted): wait the 8 OLDEST loads (= all K); V stays in
        // flight and is drained for free by barrier 2 after QK+mask+exp.
        __asm__ __volatile__("s_waitcnt vmcnt(8)" ::: "memory");
        __builtin_amdgcn_sched_barrier(0);
        __builtin_amdgcn_s_barrier();
        __builtin_amdgcn_sched_barrier(0);

        // ---- S^T = K * Q^T (K frags from swizzled LDS) ----
        fx4 sacc[4][2];
#pragma unroll
        for (int kt = 0; kt < 4; ++kt)
#pragma unroll
            for (int qt = 0; qt < 2; ++qt)
                sacc[kt][qt] = zero4;
#pragma unroll
        for (int kc = 0; kc < 4; ++kc)
#pragma unroll
            for (int kt = 0; kt < 4; ++kt) {
                bf16x8 kf = *(const bf16x8*)&Ks[(kt * 16 + l15) * 128 + (((kc * 4 + quad) ^ l15)) * 8];
#pragma unroll
                for (int qt = 0; qt < 2; ++qt)
                    sacc[kt][qt] = __builtin_amdgcn_mfma_f32_16x16x32_bf16(
                        kf, qf[qt][kc], sacc[kt][qt], 0, 0, 0);
            }

        // ---- causal mask on the diagonal block (log2-domain scores) ----
        if (kb == qb) {
#pragma unroll
            for (int kt = 0; kt < 4; ++kt)
#pragma unroll
                for (int qt = 0; qt < 2; ++qt)
#pragma unroll
                    for (int r = 0; r < 4; ++r) {
                        const int k_in = kt * 16 + quad * 4 + r;
                        const int q_in = rh * 32 + qt * 16 + l15;
                        if (q_in < k_in) sacc[kt][qt][r] = -1e30f;
                    }
        }

        // ---- no-max softmax: p = 2^s (no row reduce — l comes from MFMA) ----
#pragma unroll
        for (int kt = 0; kt < 4; ++kt)
#pragma unroll
            for (int qt = 0; qt < 2; ++qt)
#pragma unroll
                for (int r = 0; r < 4; ++r)
                    sacc[kt][qt][r] = exp2f(sacc[kt][qt][r]);

        __syncthreads();   // barrier 2: drains V DMA (had QK+mask+exp to land)
                           // + all K reads done before P overlays Ks

        // ---- P -> wave-private LDS overlay, re-read as B-operand frags ----
#pragma unroll
        for (int qt = 0; qt < 2; ++qt)
#pragma unroll
            for (int kt = 0; kt < 4; ++kt) {
                bf16x4 f = { (bf16_t)sacc[kt][qt][0], (bf16_t)sacc[kt][qt][1],
                             (bf16_t)sacc[kt][qt][2], (bf16_t)sacc[kt][qt][3] };
                *(bf16x4*)&Pt[(qt * 16 + l15) * 72 + kt * 16 + quad * 4] = f;
            }
        __asm__ __volatile__("s_waitcnt lgkmcnt(0)" ::: "memory");

        bf16x8 pf[2][2];
#pragma unroll
        for (int qt = 0; qt < 2; ++qt)
#pragma unroll
            for (int kcg = 0; kcg < 2; ++kcg)
                pf[qt][kcg] = *(const bf16x8*)&Pt[(qt * 16 + l15) * 72 + kcg * 32 + quad * 8];

        // ---- O^T += V^T * P^T ; l += ones * P^T (V frags from swizzled LDS) ----
#pragma unroll
        for (int kcg = 0; kcg < 2; ++kcg) {
#pragma unroll
            for (int dt = 0; dt < 8; ++dt) {
                bf16x8 vf = *(const bf16x8*)&Vs[(dt * 16 + l15) * 64 + (((kcg * 4 + quad) ^ (l15 & 7))) * 8];
#pragma unroll
                for (int qt = 0; qt < 2; ++qt)
                    oacc[dt][qt] = __builtin_amdgcn_mfma_f32_16x16x32_bf16(
                        vf, pf[qt][kcg], oacc[dt][qt], 0, 0, 0);
            }
#pragma unroll
            for (int qt = 0; qt < 2; ++qt)
                lacc[qt] = __builtin_amdgcn_mfma_f32_16x16x32_bf16(
                    ones, pf[qt][kcg], lacc[qt], 0, 0, 0);
        }

        __syncthreads();   // barrier 3: Vs/P reads done before next DMA
    }

    // ---- epilogue: each wave stores its own 32 rows ----
    const float inv0 = 1.0f / lacc[0][0];   // all rows of lacc are identical
    const float inv1 = 1.0f / lacc[1][0];
#pragma unroll
    for (int dt = 0; dt < 8; ++dt)
#pragma unroll
        for (int qt = 0; qt < 2; ++qt) {
            const float inv = qt ? inv1 : inv0;
            fx4 o = oacc[dt][qt] * inv;
            *(fx4*)(O + (size_t)(row0 + qt * 16 + l15) * 4096 + h * 128 + dt * 16 + quad * 4) = o;
        }
}

extern "C" void kernel_launch(void* const* d_in, const int* in_sizes, int n_in,
                              void* d_out, int out_size, void* d_ws, size_t ws_size,
                              hipStream_t stream) {
    (void)in_sizes; (void)n_in; (void)ws_size; (void)out_size;
    const float* q = (const float*)d_in[0];
    const float* k = (const float*)d_in[1];
    const float* v = (const float*)d_in[2];
    float* o = (float*)d_out;

    bf16_t* Kb = (bf16_t*)d_ws;                       // [2048][1024] bf16 = 4 MB
    bf16_t* VT = Kb + (size_t)2048 * 1024;            // [1024][2048] bf16 = 4 MB

    prep_kernel<<<dim3(512), dim3(256), 0, stream>>>(k, v, Kb, VT);
    bsfa_kernel<<<dim3(1024), dim3(128), 0, stream>>>(q, Kb, VT, o);
}